// Round 1
// baseline (1665.023 us; speedup 1.0000x reference)
//
#include <hip/hip_runtime.h>
#include <cstddef>

#define NB 64
#define NP 1024
#define NPTS (NB * NP)
#define NC 64

// ---------------------------------------------------------------------------
// Kernel 1: top-6 kNN per point (self included). One block = 256 points of one
// graph; all 1024 graph positions (+|p|^2) staged in LDS as float4.
// Stored neighbor indices are ABSOLUTE point indices.
// ---------------------------------------------------------------------------
__global__ __launch_bounds__(256) void knn6_kernel(const float* __restrict__ pos,
                                                   int* __restrict__ idx)
{
    __shared__ float4 pts[NP];
    const int b = blockIdx.x >> 2;
    const int chunk = blockIdx.x & 3;
    const int t = threadIdx.x;
    const float* gp = pos + (size_t)b * NP * 3;
    for (int q = t; q < NP; q += 256) {
        float x = gp[q * 3 + 0], y = gp[q * 3 + 1], z = gp[q * 3 + 2];
        pts[q] = make_float4(x, y, z, x * x + y * y + z * z);
    }
    __syncthreads();

    const int i = chunk * 256 + t;
    const float4 pi = pts[i];
    const float sqi = pi.w;

    float d0 = 1e30f, d1 = 1e30f, d2v = 1e30f, d3 = 1e30f, d4 = 1e30f, d5 = 1e30f;
    int i0 = 0, i1 = 0, i2 = 0, i3 = 0, i4 = 0, i5 = 0;

    for (int q = 0; q < NP; ++q) {
        float4 pq = pts[q];
        float dot = pi.x * pq.x + pi.y * pq.y + pi.z * pq.z;
        float dq = sqi + pq.w - 2.0f * dot;
        if (dq < d5) {
            if (dq < d4) {
                d5 = d4; i5 = i4;
                if (dq < d3) {
                    d4 = d3; i4 = i3;
                    if (dq < d2v) {
                        d3 = d2v; i3 = i2;
                        if (dq < d1) {
                            d2v = d1; i2 = i1;
                            if (dq < d0) {
                                d1 = d0; i1 = i0; d0 = dq; i0 = q;
                            } else { d1 = dq; i1 = q; }
                        } else { d2v = dq; i2 = q; }
                    } else { d3 = dq; i3 = q; }
                } else { d4 = dq; i4 = q; }
            } else { d5 = dq; i5 = q; }
        }
    }

    const int gb = b * NP;
    int* op = idx + (size_t)(gb + i) * 6;
    op[0] = gb + i0; op[1] = gb + i1; op[2] = gb + i2;
    op[3] = gb + i3; op[4] = gb + i4; op[5] = gb + i5;
}

// ---------------------------------------------------------------------------
// Kernel 2: layer 1 (Cin = 3, h == pos, K = 6). Wave-per-point, lane = channel.
// W1 column (9) + W2 column (64) + biases live in VGPRs; hidden vector is
// exchanged through a per-wave LDS row read back as float4 broadcasts.
// ---------------------------------------------------------------------------
__global__ __launch_bounds__(256) void layer1_kernel(
    const float* __restrict__ pos, const int* __restrict__ idx,
    const float* __restrict__ W1, const float* __restrict__ b1,
    const float* __restrict__ W2, const float* __restrict__ b2,
    float* __restrict__ hout)
{
    __shared__ float hid[4][64];
    const int t = threadIdx.x;
    const int lane = t & 63;
    const int wv = __builtin_amdgcn_readfirstlane(t >> 6);

    float w1r[9];
#pragma unroll
    for (int f = 0; f < 9; ++f) w1r[f] = W1[f * 64 + lane];
    const float b1r = b1[lane], b2r = b2[lane];
    float w2r[64];
#pragma unroll
    for (int h = 0; h < 64; ++h) w2r[h] = W2[h * 64 + lane];

    const float4* hvv = (const float4*)(&hid[wv][0]);
    const int base = blockIdx.x * 64 + wv * 16;

    for (int n = 0; n < 16; ++n) {
        const int i = base + n;
        const int* ip = idx + (size_t)i * 6;
        const float pix = pos[i * 3 + 0], piy = pos[i * 3 + 1], piz = pos[i * 3 + 2];
        float mx = -1e30f;
#pragma unroll
        for (int k = 0; k < 6; ++k) {
            const int j = __builtin_amdgcn_readfirstlane(ip[k]);
            const float pjx = pos[j * 3 + 0], pjy = pos[j * 3 + 1], pjz = pos[j * 3 + 2];
            const float rx = pjx - pix, ry = pjy - piy, rz = pjz - piz;
            float acc = b1r
                + pix * w1r[0] + piy * w1r[1] + piz * w1r[2]
                + pjx * w1r[3] + pjy * w1r[4] + pjz * w1r[5]
                + rx * w1r[6] + ry * w1r[7] + rz * w1r[8];
            const float hval = fmaxf(acc, 0.0f);
            hid[wv][lane] = hval;
            float z = b2r;
#pragma unroll
            for (int h4 = 0; h4 < 16; ++h4) {
                float4 v = hvv[h4];
                z += v.x * w2r[4 * h4 + 0] + v.y * w2r[4 * h4 + 1]
                   + v.z * w2r[4 * h4 + 2] + v.w * w2r[4 * h4 + 3];
            }
            mx = fmaxf(mx, z);
        }
        hout[(size_t)i * 64 + lane] = fmaxf(mx, 0.0f);
    }
}

// ---------------------------------------------------------------------------
// Kernel 3: layers 2/3 (Cin = 64, F = 131, K = 4 or 3). Wave-per-point.
// W1 rows 0..127 transposed into LDS (row stride 132 -> lane start bank 4c%32,
// conflict-friendly b128 reads); rows 128..130 (rel) + W2 column in VGPRs.
// Feature rows (h_i, h_j) fetched via wave-uniform pointers -> s_load.
// ---------------------------------------------------------------------------
template <int K>
__global__ __launch_bounds__(256) void layer_cin64_kernel(
    const float* __restrict__ hin, const float* __restrict__ pos,
    const int* __restrict__ idx,
    const float* __restrict__ W1, const float* __restrict__ b1,
    const float* __restrict__ W2, const float* __restrict__ b2,
    float* __restrict__ hout)
{
    __shared__ float w1t[64 * 132];
    __shared__ float hid[4][64];
    const int t = threadIdx.x;
    const int lane = t & 63;
    const int wv = __builtin_amdgcn_readfirstlane(t >> 6);

    for (int u = t; u < 128 * 64; u += 256) {
        const int f = u >> 6, c = u & 63;
        w1t[c * 132 + f] = W1[u];
    }
    const float w1c0 = W1[128 * 64 + lane];
    const float w1c1 = W1[129 * 64 + lane];
    const float w1c2 = W1[130 * 64 + lane];
    const float b1r = b1[lane], b2r = b2[lane];
    float w2r[64];
#pragma unroll
    for (int h = 0; h < 64; ++h) w2r[h] = W2[h * 64 + lane];
    __syncthreads();

    const float4* wrow = (const float4*)(&w1t[lane * 132]);
    const float4* hvv = (const float4*)(&hid[wv][0]);
    const int base = blockIdx.x * 64 + wv * 16;

    for (int n = 0; n < 16; ++n) {
        const int i = base + n;
        const int* ip = idx + (size_t)i * 6;
        const float* hi = hin + (size_t)i * 64;
        const float4* hi4 = (const float4*)hi;
        const float pix = pos[i * 3 + 0], piy = pos[i * 3 + 1], piz = pos[i * 3 + 2];
        float mx = -1e30f;
        for (int k = 0; k < K; ++k) {
            const int j = __builtin_amdgcn_readfirstlane(ip[k]);
            const float4* hj4 = (const float4*)(hin + (size_t)j * 64);
            const float rx = pos[j * 3 + 0] - pix;
            const float ry = pos[j * 3 + 1] - piy;
            const float rz = pos[j * 3 + 2] - piz;
            float acc = b1r + rx * w1c0 + ry * w1c1 + rz * w1c2;
#pragma unroll
            for (int f4 = 0; f4 < 16; ++f4) {
                float4 s = hi4[f4];
                float4 w = wrow[f4];
                acc += s.x * w.x + s.y * w.y + s.z * w.z + s.w * w.w;
            }
#pragma unroll
            for (int f4 = 0; f4 < 16; ++f4) {
                float4 s = hj4[f4];
                float4 w = wrow[16 + f4];
                acc += s.x * w.x + s.y * w.y + s.z * w.z + s.w * w.w;
            }
            const float hval = fmaxf(acc, 0.0f);
            hid[wv][lane] = hval;
            float z = b2r;
#pragma unroll
            for (int h4 = 0; h4 < 16; ++h4) {
                float4 v = hvv[h4];
                z += v.x * w2r[4 * h4 + 0] + v.y * w2r[4 * h4 + 1]
                   + v.z * w2r[4 * h4 + 2] + v.w * w2r[4 * h4 + 3];
            }
            mx = fmaxf(mx, z);
        }
        hout[(size_t)i * 64 + lane] = fmaxf(mx, 0.0f);
    }
}

// ---------------------------------------------------------------------------
// Kernel 4: global max pool over points + 64->6 regression. One block/graph.
// ---------------------------------------------------------------------------
__global__ __launch_bounds__(256) void pool_reg_kernel(
    const float* __restrict__ h3, const float* __restrict__ regW,
    const float* __restrict__ regb, float* __restrict__ out)
{
    __shared__ float red[4][64];
    __shared__ float pooled[64];
    const int b = blockIdx.x;
    const int t = threadIdx.x;
    const int c = t & 63;
    const int seg = t >> 6;
    const float* hb = h3 + (size_t)b * NP * NC;
    float m = -1e30f;
    for (int p = seg; p < NP; p += 4) m = fmaxf(m, hb[(size_t)p * 64 + c]);
    red[seg][c] = m;
    __syncthreads();
    if (t < 64) {
        pooled[t] = fmaxf(fmaxf(red[0][t], red[1][t]), fmaxf(red[2][t], red[3][t]));
    }
    __syncthreads();
    if (t < 6) {
        float z = regb[t];
        for (int cc = 0; cc < 64; ++cc) z += pooled[cc] * regW[cc * 6 + t];
        out[b * 6 + t] = z;
    }
}

// ---------------------------------------------------------------------------
extern "C" void kernel_launch(void* const* d_in, const int* in_sizes, int n_in,
                              void* d_out, int out_size, void* d_ws, size_t ws_size,
                              hipStream_t stream)
{
    (void)in_sizes; (void)n_in; (void)out_size; (void)ws_size;
    // inputs: 0:x 1:pos 2:batch 3..6:conv1 7..10:conv2 11..14:conv3 15:regW 16:regb
    const float* pos   = (const float*)d_in[1];
    const float* c1W1  = (const float*)d_in[3];
    const float* c1b1  = (const float*)d_in[4];
    const float* c1W2  = (const float*)d_in[5];
    const float* c1b2  = (const float*)d_in[6];
    const float* c2W1  = (const float*)d_in[7];
    const float* c2b1  = (const float*)d_in[8];
    const float* c2W2  = (const float*)d_in[9];
    const float* c2b2  = (const float*)d_in[10];
    const float* c3W1  = (const float*)d_in[11];
    const float* c3b1  = (const float*)d_in[12];
    const float* c3W2  = (const float*)d_in[13];
    const float* c3b2  = (const float*)d_in[14];
    const float* regW  = (const float*)d_in[15];
    const float* regb  = (const float*)d_in[16];
    float* out = (float*)d_out;

    char* ws = (char*)d_ws;
    int*   idx = (int*)ws;                                   // 65536*6*4 = 1572864 B
    float* h1  = (float*)(ws + 1572864);                     // 16777216 B
    float* h2  = (float*)(ws + 1572864 + 16777216);          // 16777216 B
    float* h3  = h1;                                         // reuse h1 region

    knn6_kernel<<<NB * 4, 256, 0, stream>>>(pos, idx);
    layer1_kernel<<<NPTS / 64, 256, 0, stream>>>(pos, idx, c1W1, c1b1, c1W2, c1b2, h1);
    layer_cin64_kernel<4><<<NPTS / 64, 256, 0, stream>>>(h1, pos, idx, c2W1, c2b1, c2W2, c2b2, h2);
    layer_cin64_kernel<3><<<NPTS / 64, 256, 0, stream>>>(h2, pos, idx, c3W1, c3b1, c3W2, c3b2, h3);
    pool_reg_kernel<<<NB, 256, 0, stream>>>(h3, regW, regb, out);
}

// Round 2
// 548.305 us; speedup vs baseline: 3.0367x; 3.0367x over previous
//
#include <hip/hip_runtime.h>
#include <cstddef>

#define NB 64
#define NP 1024
#define NPTS (NB * NP)

__device__ __forceinline__ float bcastf(float v, int l) {
    return __int_as_float(__builtin_amdgcn_readlane(__float_as_int(v), l));
}

// ---------------------------------------------------------------------------
// Kernel 1: top-6 kNN per point (self included, stable tie order). One block =
// 256 points of one graph; 1024 positions (+|p|^2) staged in LDS as float4.
// Stored neighbor indices are ABSOLUTE point indices.
// ---------------------------------------------------------------------------
__global__ __launch_bounds__(256) void knn6_kernel(const float* __restrict__ pos,
                                                   int* __restrict__ idx)
{
    __shared__ float4 pts[NP];
    const int b = blockIdx.x >> 2;
    const int chunk = blockIdx.x & 3;
    const int t = threadIdx.x;
    const float* gp = pos + (size_t)b * NP * 3;
    for (int q = t; q < NP; q += 256) {
        float x = gp[q * 3 + 0], y = gp[q * 3 + 1], z = gp[q * 3 + 2];
        pts[q] = make_float4(x, y, z, x * x + y * y + z * z);
    }
    __syncthreads();

    const int i = chunk * 256 + t;
    const float4 pi = pts[i];
    const float sqi = pi.w;

    float d0 = 1e30f, d1 = 1e30f, d2v = 1e30f, d3 = 1e30f, d4 = 1e30f, d5 = 1e30f;
    int i0 = 0, i1 = 0, i2 = 0, i3 = 0, i4 = 0, i5 = 0;

    for (int q = 0; q < NP; ++q) {
        float4 pq = pts[q];
        float dot = pi.x * pq.x + pi.y * pq.y + pi.z * pq.z;
        float dq = sqi + pq.w - 2.0f * dot;
        if (dq < d5) {
            if (dq < d4) {
                d5 = d4; i5 = i4;
                if (dq < d3) {
                    d4 = d3; i4 = i3;
                    if (dq < d2v) {
                        d3 = d2v; i3 = i2;
                        if (dq < d1) {
                            d2v = d1; i2 = i1;
                            if (dq < d0) {
                                d1 = d0; i1 = i0; d0 = dq; i0 = q;
                            } else { d1 = dq; i1 = q; }
                        } else { d2v = dq; i2 = q; }
                    } else { d3 = dq; i3 = q; }
                } else { d4 = dq; i4 = q; }
            } else { d5 = dq; i5 = q; }
        }
    }

    const int gb = b * NP;
    int* op = idx + (size_t)(gb + i) * 6;
    op[0] = gb + i0; op[1] = gb + i1; op[2] = gb + i2;
    op[3] = gb + i3; op[4] = gb + i4; op[5] = gb + i5;
}

// ---------------------------------------------------------------------------
// Kernel 2: U/V precompute for Cin=64 layers.
//   U[i][c] = b1[c] + sum_h H[i][h] * W1[h][c]        (rows 0..63, in-place)
//   V[i][c] =         sum_h H[i][h] * W1[64+h][c]     (rows 64..127)
// Wave-per-point, lane = channel. H row in lane regs, broadcast via readlane.
// In-place U write is safe: the wave reads its own row fully before writing.
// ---------------------------------------------------------------------------
__global__ __launch_bounds__(256) void uv_kernel(
    float* __restrict__ h,            // in: H, out: U (in place)
    float* __restrict__ Vout,
    const float* __restrict__ W1, const float* __restrict__ b1)
{
    const int t = threadIdx.x;
    const int lane = t & 63;
    const int wv = __builtin_amdgcn_readfirstlane(t >> 6);

    float w1a[64], w1b[64];
#pragma unroll
    for (int k = 0; k < 64; ++k) w1a[k] = W1[k * 64 + lane];
#pragma unroll
    for (int k = 0; k < 64; ++k) w1b[k] = W1[(64 + k) * 64 + lane];
    const float b1r = b1[lane];

    const int base = blockIdx.x * 64 + wv * 16;
    for (int n = 0; n < 16; ++n) {
        const int i = base + n;
        const float tv = h[(size_t)i * 64 + lane];
        float zu0 = b1r, zu1 = 0.f, zv0 = 0.f, zv1 = 0.f;
#pragma unroll
        for (int k = 0; k < 64; k += 2) {
            const float s0 = bcastf(tv, k + 0);
            const float s1 = bcastf(tv, k + 1);
            zu0 = fmaf(s0, w1a[k + 0], zu0);
            zv0 = fmaf(s0, w1b[k + 0], zv0);
            zu1 = fmaf(s1, w1a[k + 1], zu1);
            zv1 = fmaf(s1, w1b[k + 1], zv1);
        }
        h[(size_t)i * 64 + lane] = zu0 + zu1;
        Vout[(size_t)i * 64 + lane] = zv0 + zv1;
    }
}

// ---------------------------------------------------------------------------
// Kernel 3: fused edge + W2 + neighbor-max for Cin=64 layers (K = 4 or 3).
// Wave-per-point, lane = channel. t = relu(U[i] + V[j] + rel*W1c); then
// z = t @ W2 via 64 readlane broadcasts into 4 FMA chains. No LDS.
// ---------------------------------------------------------------------------
template <int K>
__global__ __launch_bounds__(256) void edge64_kernel(
    const float* __restrict__ U, const float* __restrict__ V,
    const float* __restrict__ pos, const int* __restrict__ idx,
    const float* __restrict__ W1,
    const float* __restrict__ W2, const float* __restrict__ b2,
    float* __restrict__ hout)
{
    const int t = threadIdx.x;
    const int lane = t & 63;
    const int wv = __builtin_amdgcn_readfirstlane(t >> 6);

    const float w1c0 = W1[128 * 64 + lane];
    const float w1c1 = W1[129 * 64 + lane];
    const float w1c2 = W1[130 * 64 + lane];
    const float b2r = b2[lane];
    float w2r[64];
#pragma unroll
    for (int h = 0; h < 64; ++h) w2r[h] = W2[h * 64 + lane];

    const int base = blockIdx.x * 64 + wv * 16;
    for (int n = 0; n < 16; ++n) {
        const int i = base + n;
        const float u = U[(size_t)i * 64 + lane];
        const float pix = pos[i * 3 + 0], piy = pos[i * 3 + 1], piz = pos[i * 3 + 2];
        const int* ip = idx + (size_t)i * 6;
        float mx = -1e30f;
#pragma unroll
        for (int k = 0; k < K; ++k) {
            const int j = __builtin_amdgcn_readfirstlane(ip[k]);
            const float v = V[(size_t)j * 64 + lane];
            const float rx = pos[j * 3 + 0] - pix;
            const float ry = pos[j * 3 + 1] - piy;
            const float rz = pos[j * 3 + 2] - piz;
            float tf = u + v + rx * w1c0 + ry * w1c1 + rz * w1c2;
            tf = fmaxf(tf, 0.0f);
            float z0 = b2r, z1 = 0.f, z2 = 0.f, z3 = 0.f;
#pragma unroll
            for (int h = 0; h < 64; h += 4) {
                z0 = fmaf(bcastf(tf, h + 0), w2r[h + 0], z0);
                z1 = fmaf(bcastf(tf, h + 1), w2r[h + 1], z1);
                z2 = fmaf(bcastf(tf, h + 2), w2r[h + 2], z2);
                z3 = fmaf(bcastf(tf, h + 3), w2r[h + 3], z3);
            }
            mx = fmaxf(mx, (z0 + z1) + (z2 + z3));
        }
        hout[(size_t)i * 64 + lane] = fmaxf(mx, 0.0f);
    }
}

// ---------------------------------------------------------------------------
// Kernel 4: layer 1 (Cin = 3, h == pos, K = 6). Same structure, W1 is 9x64.
// ---------------------------------------------------------------------------
__global__ __launch_bounds__(256) void edge3_kernel(
    const float* __restrict__ pos, const int* __restrict__ idx,
    const float* __restrict__ W1, const float* __restrict__ b1,
    const float* __restrict__ W2, const float* __restrict__ b2,
    float* __restrict__ hout)
{
    const int t = threadIdx.x;
    const int lane = t & 63;
    const int wv = __builtin_amdgcn_readfirstlane(t >> 6);

    float w1r[9];
#pragma unroll
    for (int f = 0; f < 9; ++f) w1r[f] = W1[f * 64 + lane];
    const float b1r = b1[lane], b2r = b2[lane];
    float w2r[64];
#pragma unroll
    for (int h = 0; h < 64; ++h) w2r[h] = W2[h * 64 + lane];

    const int base = blockIdx.x * 64 + wv * 16;
    for (int n = 0; n < 16; ++n) {
        const int i = base + n;
        const float pix = pos[i * 3 + 0], piy = pos[i * 3 + 1], piz = pos[i * 3 + 2];
        const float u = b1r + pix * w1r[0] + piy * w1r[1] + piz * w1r[2];
        const int* ip = idx + (size_t)i * 6;
        float mx = -1e30f;
#pragma unroll
        for (int k = 0; k < 6; ++k) {
            const int j = __builtin_amdgcn_readfirstlane(ip[k]);
            const float pjx = pos[j * 3 + 0], pjy = pos[j * 3 + 1], pjz = pos[j * 3 + 2];
            const float rx = pjx - pix, ry = pjy - piy, rz = pjz - piz;
            float tf = u + pjx * w1r[3] + pjy * w1r[4] + pjz * w1r[5]
                         + rx * w1r[6] + ry * w1r[7] + rz * w1r[8];
            tf = fmaxf(tf, 0.0f);
            float z0 = b2r, z1 = 0.f, z2 = 0.f, z3 = 0.f;
#pragma unroll
            for (int h = 0; h < 64; h += 4) {
                z0 = fmaf(bcastf(tf, h + 0), w2r[h + 0], z0);
                z1 = fmaf(bcastf(tf, h + 1), w2r[h + 1], z1);
                z2 = fmaf(bcastf(tf, h + 2), w2r[h + 2], z2);
                z3 = fmaf(bcastf(tf, h + 3), w2r[h + 3], z3);
            }
            mx = fmaxf(mx, (z0 + z1) + (z2 + z3));
        }
        hout[(size_t)i * 64 + lane] = fmaxf(mx, 0.0f);
    }
}

// ---------------------------------------------------------------------------
// Kernel 5: global max pool over points + 64->6 regression. One block/graph.
// ---------------------------------------------------------------------------
__global__ __launch_bounds__(256) void pool_reg_kernel(
    const float* __restrict__ h3, const float* __restrict__ regW,
    const float* __restrict__ regb, float* __restrict__ out)
{
    __shared__ float red[4][64];
    __shared__ float pooled[64];
    const int b = blockIdx.x;
    const int t = threadIdx.x;
    const int c = t & 63;
    const int seg = t >> 6;
    const float* hb = h3 + (size_t)b * NP * 64;
    float m = -1e30f;
    for (int p = seg; p < NP; p += 4) m = fmaxf(m, hb[(size_t)p * 64 + c]);
    red[seg][c] = m;
    __syncthreads();
    if (t < 64) {
        pooled[t] = fmaxf(fmaxf(red[0][t], red[1][t]), fmaxf(red[2][t], red[3][t]));
    }
    __syncthreads();
    if (t < 6) {
        float z = regb[t];
        for (int cc = 0; cc < 64; ++cc) z += pooled[cc] * regW[cc * 6 + t];
        out[b * 6 + t] = z;
    }
}

// ---------------------------------------------------------------------------
extern "C" void kernel_launch(void* const* d_in, const int* in_sizes, int n_in,
                              void* d_out, int out_size, void* d_ws, size_t ws_size,
                              hipStream_t stream)
{
    (void)in_sizes; (void)n_in; (void)out_size; (void)ws_size;
    const float* pos   = (const float*)d_in[1];
    const float* c1W1  = (const float*)d_in[3];
    const float* c1b1  = (const float*)d_in[4];
    const float* c1W2  = (const float*)d_in[5];
    const float* c1b2  = (const float*)d_in[6];
    const float* c2W1  = (const float*)d_in[7];
    const float* c2b1  = (const float*)d_in[8];
    const float* c2W2  = (const float*)d_in[9];
    const float* c2b2  = (const float*)d_in[10];
    const float* c3W1  = (const float*)d_in[11];
    const float* c3b1  = (const float*)d_in[12];
    const float* c3W2  = (const float*)d_in[13];
    const float* c3b2  = (const float*)d_in[14];
    const float* regW  = (const float*)d_in[15];
    const float* regb  = (const float*)d_in[16];
    float* out = (float*)d_out;

    // workspace layout: idx | A | C | D  (A,C,D are 65536x64 fp32)
    char* ws = (char*)d_ws;
    int*   idx = (int*)ws;                                    // 1572864 B
    float* A = (float*)(ws + 1572864);                        // 16777216 B
    float* C = (float*)(ws + 1572864 + 16777216);             // 16777216 B
    float* D = (float*)(ws + 1572864 + 2 * 16777216);         // 16777216 B

    knn6_kernel<<<NB * 4, 256, 0, stream>>>(pos, idx);
    // layer 1 -> A (= h1)
    edge3_kernel<<<NPTS / 64, 256, 0, stream>>>(pos, idx, c1W1, c1b1, c1W2, c1b2, A);
    // layer 2: U2 in-place over A, V2 -> C; edges -> D (= h2)
    uv_kernel<<<NPTS / 64, 256, 0, stream>>>(A, C, c2W1, c2b1);
    edge64_kernel<4><<<NPTS / 64, 256, 0, stream>>>(A, C, pos, idx, c2W1, c2W2, c2b2, D);
    // layer 3: U3 in-place over D, V3 -> C; edges -> A (= h3)
    uv_kernel<<<NPTS / 64, 256, 0, stream>>>(D, C, c3W1, c3b1);
    edge64_kernel<3><<<NPTS / 64, 256, 0, stream>>>(D, C, pos, idx, c3W1, c3W2, c3b2, A);
    // pool + regression
    pool_reg_kernel<<<NB, 256, 0, stream>>>(A, regW, regb, out);
}

// Round 3
// 457.666 us; speedup vs baseline: 3.6381x; 1.1980x over previous
//
#include <hip/hip_runtime.h>
#include <cstddef>

#define NB 64
#define NP 1024
#define NPTS (NB * NP)

__device__ __forceinline__ float bcastf(float v, int l) {
    return __int_as_float(__builtin_amdgcn_readlane(__float_as_int(v), l));
}

// ---------------------------------------------------------------------------
// Kernel 1: top-6 kNN per point (self included, top_k-stable tie order).
// One block = 64 points of one graph, 4 scanner threads per point (strided
// candidates, conflict-free LDS banks), private top-6 each, then a
// lexicographic (d2, index) merge -- identical selection to jax.lax.top_k.
// Stored neighbor indices are ABSOLUTE point indices.
// ---------------------------------------------------------------------------
__global__ __launch_bounds__(256) void knn6_kernel(const float* __restrict__ pos,
                                                   int* __restrict__ idx)
{
    __shared__ float4 pts[NP];
    __shared__ float md[64][4][6];
    __shared__ int   mi[64][4][6];

    const int blk = blockIdx.x;
    const int b = blk >> 4;
    const int chunk = blk & 15;
    const int t = threadIdx.x;
    const float* gp = pos + (size_t)b * NP * 3;
    for (int q = t; q < NP; q += 256) {
        float x = gp[q * 3 + 0], y = gp[q * 3 + 1], z = gp[q * 3 + 2];
        pts[q] = make_float4(x, y, z, x * x + y * y + z * z);
    }
    __syncthreads();

    const int p = t >> 2;          // local point 0..63
    const int sub = t & 3;         // scanner id 0..3
    const int il = chunk * 64 + p; // graph-local query index
    const float4 pi = pts[il];
    const float sqi = pi.w;

    float d0 = 1e30f, d1 = 1e30f, d2v = 1e30f, d3 = 1e30f, d4 = 1e30f, d5 = 1e30f;
    int i0 = 0, i1 = 0, i2 = 0, i3 = 0, i4 = 0, i5 = 0;

    for (int it = 0; it < 256; ++it) {
        const int q = (it << 2) | sub;
        float4 pq = pts[q];
        float dot = pi.x * pq.x + pi.y * pq.y + pi.z * pq.z;
        float dq = sqi + pq.w - 2.0f * dot;
        if (dq < d5) {
            if (dq < d4) {
                d5 = d4; i5 = i4;
                if (dq < d3) {
                    d4 = d3; i4 = i3;
                    if (dq < d2v) {
                        d3 = d2v; i3 = i2;
                        if (dq < d1) {
                            d2v = d1; i2 = i1;
                            if (dq < d0) {
                                d1 = d0; i1 = i0; d0 = dq; i0 = q;
                            } else { d1 = dq; i1 = q; }
                        } else { d2v = dq; i2 = q; }
                    } else { d3 = dq; i3 = q; }
                } else { d4 = dq; i4 = q; }
            } else { d5 = dq; i5 = q; }
        }
    }

    md[p][sub][0] = d0; md[p][sub][1] = d1; md[p][sub][2] = d2v;
    md[p][sub][3] = d3; md[p][sub][4] = d4; md[p][sub][5] = d5;
    mi[p][sub][0] = i0; mi[p][sub][1] = i1; mi[p][sub][2] = i2;
    mi[p][sub][3] = i3; mi[p][sub][4] = i4; mi[p][sub][5] = i5;
    __syncthreads();

    if (t < 64) {
        float e0 = 1e30f, e1 = 1e30f, e2 = 1e30f, e3 = 1e30f, e4 = 1e30f, e5 = 1e30f;
        int j0 = 0x7fffffff, j1 = 0x7fffffff, j2 = 0x7fffffff,
            j3 = 0x7fffffff, j4 = 0x7fffffff, j5 = 0x7fffffff;
#pragma unroll
        for (int s = 0; s < 4; ++s) {
#pragma unroll
            for (int k = 0; k < 6; ++k) {
                const float d = md[t][s][k];
                const int q = mi[t][s][k];
                // lexicographic (d, q) insertion == stable top_k tie rule
                if (d < e5 || (d == e5 && q < j5)) {
                    if (d < e4 || (d == e4 && q < j4)) {
                        e5 = e4; j5 = j4;
                        if (d < e3 || (d == e3 && q < j3)) {
                            e4 = e3; j4 = j3;
                            if (d < e2 || (d == e2 && q < j2)) {
                                e3 = e2; j3 = j2;
                                if (d < e1 || (d == e1 && q < j1)) {
                                    e2 = e1; j2 = j1;
                                    if (d < e0 || (d == e0 && q < j0)) {
                                        e1 = e0; j1 = j0; e0 = d; j0 = q;
                                    } else { e1 = d; j1 = q; }
                                } else { e2 = d; j2 = q; }
                            } else { e3 = d; j3 = q; }
                        } else { e4 = d; j4 = q; }
                    } else { e5 = d; j5 = q; }
                }
            }
        }
        const int gb = b * NP;
        int* op = idx + (size_t)(gb + chunk * 64 + t) * 6;
        op[0] = gb + j0; op[1] = gb + j1; op[2] = gb + j2;
        op[3] = gb + j3; op[4] = gb + j4; op[5] = gb + j5;
    }
}

// ---------------------------------------------------------------------------
// Kernel 2: U/V precompute for Cin=64 layers.
//   U[i][c] = b1[c] + sum_h H[i][h] * W1[h][c]        (rows 0..63, in-place)
//   V[i][c] =         sum_h H[i][h] * W1[64+h][c]     (rows 64..127)
// Wave-per-point, lane = channel. H row in lane regs, broadcast via readlane.
// ---------------------------------------------------------------------------
__global__ __launch_bounds__(256) void uv_kernel(
    float* __restrict__ h,            // in: H, out: U (in place)
    float* __restrict__ Vout,
    const float* __restrict__ W1, const float* __restrict__ b1)
{
    const int t = threadIdx.x;
    const int lane = t & 63;
    const int wv = __builtin_amdgcn_readfirstlane(t >> 6);

    float w1a[64], w1b[64];
#pragma unroll
    for (int k = 0; k < 64; ++k) w1a[k] = W1[k * 64 + lane];
#pragma unroll
    for (int k = 0; k < 64; ++k) w1b[k] = W1[(64 + k) * 64 + lane];
    const float b1r = b1[lane];

    const int base = blockIdx.x * 64 + wv * 16;
    for (int n = 0; n < 16; ++n) {
        const int i = base + n;
        const float tv = h[(size_t)i * 64 + lane];
        float zu0 = b1r, zu1 = 0.f, zv0 = 0.f, zv1 = 0.f;
#pragma unroll
        for (int k = 0; k < 64; k += 2) {
            const float s0 = bcastf(tv, k + 0);
            const float s1 = bcastf(tv, k + 1);
            zu0 = fmaf(s0, w1a[k + 0], zu0);
            zv0 = fmaf(s0, w1b[k + 0], zv0);
            zu1 = fmaf(s1, w1a[k + 1], zu1);
            zv1 = fmaf(s1, w1b[k + 1], zv1);
        }
        h[(size_t)i * 64 + lane] = zu0 + zu1;
        Vout[(size_t)i * 64 + lane] = zv0 + zv1;
    }
}

// ---------------------------------------------------------------------------
// Kernel 3: fused edge + W2 + neighbor-max for Cin=64 layers (K = 4 or 3).
// Wave-per-point, lane = channel. t = relu(U[i] + V[j] + rel*W1c); then
// z = t @ W2 via 64 readlane broadcasts into 4 FMA chains. No LDS.
// ---------------------------------------------------------------------------
template <int K>
__global__ __launch_bounds__(256) void edge64_kernel(
    const float* __restrict__ U, const float* __restrict__ V,
    const float* __restrict__ pos, const int* __restrict__ idx,
    const float* __restrict__ W1,
    const float* __restrict__ W2, const float* __restrict__ b2,
    float* __restrict__ hout)
{
    const int t = threadIdx.x;
    const int lane = t & 63;
    const int wv = __builtin_amdgcn_readfirstlane(t >> 6);

    const float w1c0 = W1[128 * 64 + lane];
    const float w1c1 = W1[129 * 64 + lane];
    const float w1c2 = W1[130 * 64 + lane];
    const float b2r = b2[lane];
    float w2r[64];
#pragma unroll
    for (int h = 0; h < 64; ++h) w2r[h] = W2[h * 64 + lane];

    const int base = blockIdx.x * 64 + wv * 16;
    for (int n = 0; n < 16; ++n) {
        const int i = base + n;
        const float u = U[(size_t)i * 64 + lane];
        const float pix = pos[i * 3 + 0], piy = pos[i * 3 + 1], piz = pos[i * 3 + 2];
        const int* ip = idx + (size_t)i * 6;
        float mx = -1e30f;
#pragma unroll
        for (int k = 0; k < K; ++k) {
            const int j = __builtin_amdgcn_readfirstlane(ip[k]);
            const float v = V[(size_t)j * 64 + lane];
            const float rx = pos[j * 3 + 0] - pix;
            const float ry = pos[j * 3 + 1] - piy;
            const float rz = pos[j * 3 + 2] - piz;
            float tf = u + v + rx * w1c0 + ry * w1c1 + rz * w1c2;
            tf = fmaxf(tf, 0.0f);
            float z0 = b2r, z1 = 0.f, z2 = 0.f, z3 = 0.f;
#pragma unroll
            for (int h = 0; h < 64; h += 4) {
                z0 = fmaf(bcastf(tf, h + 0), w2r[h + 0], z0);
                z1 = fmaf(bcastf(tf, h + 1), w2r[h + 1], z1);
                z2 = fmaf(bcastf(tf, h + 2), w2r[h + 2], z2);
                z3 = fmaf(bcastf(tf, h + 3), w2r[h + 3], z3);
            }
            mx = fmaxf(mx, (z0 + z1) + (z2 + z3));
        }
        hout[(size_t)i * 64 + lane] = fmaxf(mx, 0.0f);
    }
}

// ---------------------------------------------------------------------------
// Kernel 4: layer 1 (Cin = 3, h == pos, K = 6). Same structure, W1 is 9x64.
// ---------------------------------------------------------------------------
__global__ __launch_bounds__(256) void edge3_kernel(
    const float* __restrict__ pos, const int* __restrict__ idx,
    const float* __restrict__ W1, const float* __restrict__ b1,
    const float* __restrict__ W2, const float* __restrict__ b2,
    float* __restrict__ hout)
{
    const int t = threadIdx.x;
    const int lane = t & 63;
    const int wv = __builtin_amdgcn_readfirstlane(t >> 6);

    float w1r[9];
#pragma unroll
    for (int f = 0; f < 9; ++f) w1r[f] = W1[f * 64 + lane];
    const float b1r = b1[lane], b2r = b2[lane];
    float w2r[64];
#pragma unroll
    for (int h = 0; h < 64; ++h) w2r[h] = W2[h * 64 + lane];

    const int base = blockIdx.x * 64 + wv * 16;
    for (int n = 0; n < 16; ++n) {
        const int i = base + n;
        const float pix = pos[i * 3 + 0], piy = pos[i * 3 + 1], piz = pos[i * 3 + 2];
        const float u = b1r + pix * w1r[0] + piy * w1r[1] + piz * w1r[2];
        const int* ip = idx + (size_t)i * 6;
        float mx = -1e30f;
#pragma unroll
        for (int k = 0; k < 6; ++k) {
            const int j = __builtin_amdgcn_readfirstlane(ip[k]);
            const float pjx = pos[j * 3 + 0], pjy = pos[j * 3 + 1], pjz = pos[j * 3 + 2];
            const float rx = pjx - pix, ry = pjy - piy, rz = pjz - piz;
            float tf = u + pjx * w1r[3] + pjy * w1r[4] + pjz * w1r[5]
                         + rx * w1r[6] + ry * w1r[7] + rz * w1r[8];
            tf = fmaxf(tf, 0.0f);
            float z0 = b2r, z1 = 0.f, z2 = 0.f, z3 = 0.f;
#pragma unroll
            for (int h = 0; h < 64; h += 4) {
                z0 = fmaf(bcastf(tf, h + 0), w2r[h + 0], z0);
                z1 = fmaf(bcastf(tf, h + 1), w2r[h + 1], z1);
                z2 = fmaf(bcastf(tf, h + 2), w2r[h + 2], z2);
                z3 = fmaf(bcastf(tf, h + 3), w2r[h + 3], z3);
            }
            mx = fmaxf(mx, (z0 + z1) + (z2 + z3));
        }
        hout[(size_t)i * 64 + lane] = fmaxf(mx, 0.0f);
    }
}

// ---------------------------------------------------------------------------
// Kernel 5: global max pool over points + 64->6 regression. One block/graph.
// ---------------------------------------------------------------------------
__global__ __launch_bounds__(256) void pool_reg_kernel(
    const float* __restrict__ h3, const float* __restrict__ regW,
    const float* __restrict__ regb, float* __restrict__ out)
{
    __shared__ float red[4][64];
    __shared__ float pooled[64];
    const int b = blockIdx.x;
    const int t = threadIdx.x;
    const int c = t & 63;
    const int seg = t >> 6;
    const float* hb = h3 + (size_t)b * NP * 64;
    float m = -1e30f;
    for (int p = seg; p < NP; p += 4) m = fmaxf(m, hb[(size_t)p * 64 + c]);
    red[seg][c] = m;
    __syncthreads();
    if (t < 64) {
        pooled[t] = fmaxf(fmaxf(red[0][t], red[1][t]), fmaxf(red[2][t], red[3][t]));
    }
    __syncthreads();
    if (t < 6) {
        float z = regb[t];
        for (int cc = 0; cc < 64; ++cc) z += pooled[cc] * regW[cc * 6 + t];
        out[b * 6 + t] = z;
    }
}

// ---------------------------------------------------------------------------
extern "C" void kernel_launch(void* const* d_in, const int* in_sizes, int n_in,
                              void* d_out, int out_size, void* d_ws, size_t ws_size,
                              hipStream_t stream)
{
    (void)in_sizes; (void)n_in; (void)out_size; (void)ws_size;
    const float* pos   = (const float*)d_in[1];
    const float* c1W1  = (const float*)d_in[3];
    const float* c1b1  = (const float*)d_in[4];
    const float* c1W2  = (const float*)d_in[5];
    const float* c1b2  = (const float*)d_in[6];
    const float* c2W1  = (const float*)d_in[7];
    const float* c2b1  = (const float*)d_in[8];
    const float* c2W2  = (const float*)d_in[9];
    const float* c2b2  = (const float*)d_in[10];
    const float* c3W1  = (const float*)d_in[11];
    const float* c3b1  = (const float*)d_in[12];
    const float* c3W2  = (const float*)d_in[13];
    const float* c3b2  = (const float*)d_in[14];
    const float* regW  = (const float*)d_in[15];
    const float* regb  = (const float*)d_in[16];
    float* out = (float*)d_out;

    // workspace layout: idx | A | C | D  (A,C,D are 65536x64 fp32)
    char* ws = (char*)d_ws;
    int*   idx = (int*)ws;                                    // 1572864 B
    float* A = (float*)(ws + 1572864);                        // 16777216 B
    float* C = (float*)(ws + 1572864 + 16777216);             // 16777216 B
    float* D = (float*)(ws + 1572864 + 2 * 16777216);         // 16777216 B

    knn6_kernel<<<NB * 16, 256, 0, stream>>>(pos, idx);
    // layer 1 -> A (= h1)
    edge3_kernel<<<NPTS / 64, 256, 0, stream>>>(pos, idx, c1W1, c1b1, c1W2, c1b2, A);
    // layer 2: U2 in-place over A, V2 -> C; edges -> D (= h2)
    uv_kernel<<<NPTS / 64, 256, 0, stream>>>(A, C, c2W1, c2b1);
    edge64_kernel<4><<<NPTS / 64, 256, 0, stream>>>(A, C, pos, idx, c2W1, c2W2, c2b2, D);
    // layer 3: U3 in-place over D, V3 -> C; edges -> A (= h3)
    uv_kernel<<<NPTS / 64, 256, 0, stream>>>(D, C, c3W1, c3b1);
    edge64_kernel<3><<<NPTS / 64, 256, 0, stream>>>(D, C, pos, idx, c3W1, c3W2, c3b2, A);
    // pool + regression
    pool_reg_kernel<<<NB, 256, 0, stream>>>(A, regW, regb, out);
}

// Round 4
// 329.590 us; speedup vs baseline: 5.0518x; 1.3886x over previous
//
#include <hip/hip_runtime.h>
#include <cstddef>

#define NB 64
#define NP 1024
#define NPTS (NB * NP)

typedef __attribute__((ext_vector_type(8))) short v8s;
typedef __attribute__((ext_vector_type(4))) float f32x4;

__device__ __forceinline__ float bcastf(float v, int l) {
    return __int_as_float(__builtin_amdgcn_readlane(__float_as_int(v), l));
}

// ---------------------------------------------------------------------------
// Kernel 1: top-6 kNN per point (self included, top_k-stable tie order).
// One block = 64 points of one graph, 4 scanner threads per point, private
// top-6 each, lexicographic (d2, index) merge == jax.lax.top_k selection.
// ---------------------------------------------------------------------------
__global__ __launch_bounds__(256) void knn6_kernel(const float* __restrict__ pos,
                                                   int* __restrict__ idx)
{
    __shared__ float4 pts[NP];
    __shared__ float md[64][4][6];
    __shared__ int   mi[64][4][6];

    const int blk = blockIdx.x;
    const int b = blk >> 4;
    const int chunk = blk & 15;
    const int t = threadIdx.x;
    const float* gp = pos + (size_t)b * NP * 3;
    for (int q = t; q < NP; q += 256) {
        float x = gp[q * 3 + 0], y = gp[q * 3 + 1], z = gp[q * 3 + 2];
        pts[q] = make_float4(x, y, z, x * x + y * y + z * z);
    }
    __syncthreads();

    const int p = t >> 2;
    const int sub = t & 3;
    const int il = chunk * 64 + p;
    const float4 pi = pts[il];
    const float sqi = pi.w;

    float d0 = 1e30f, d1 = 1e30f, d2v = 1e30f, d3 = 1e30f, d4 = 1e30f, d5 = 1e30f;
    int i0 = 0, i1 = 0, i2 = 0, i3 = 0, i4 = 0, i5 = 0;

    for (int it = 0; it < 256; ++it) {
        const int q = (it << 2) | sub;
        float4 pq = pts[q];
        float dot = pi.x * pq.x + pi.y * pq.y + pi.z * pq.z;
        float dq = sqi + pq.w - 2.0f * dot;
        if (dq < d5) {
            if (dq < d4) {
                d5 = d4; i5 = i4;
                if (dq < d3) {
                    d4 = d3; i4 = i3;
                    if (dq < d2v) {
                        d3 = d2v; i3 = i2;
                        if (dq < d1) {
                            d2v = d1; i2 = i1;
                            if (dq < d0) {
                                d1 = d0; i1 = i0; d0 = dq; i0 = q;
                            } else { d1 = dq; i1 = q; }
                        } else { d2v = dq; i2 = q; }
                    } else { d3 = dq; i3 = q; }
                } else { d4 = dq; i4 = q; }
            } else { d5 = dq; i5 = q; }
        }
    }

    md[p][sub][0] = d0; md[p][sub][1] = d1; md[p][sub][2] = d2v;
    md[p][sub][3] = d3; md[p][sub][4] = d4; md[p][sub][5] = d5;
    mi[p][sub][0] = i0; mi[p][sub][1] = i1; mi[p][sub][2] = i2;
    mi[p][sub][3] = i3; mi[p][sub][4] = i4; mi[p][sub][5] = i5;
    __syncthreads();

    if (t < 64) {
        float e0 = 1e30f, e1 = 1e30f, e2 = 1e30f, e3 = 1e30f, e4 = 1e30f, e5 = 1e30f;
        int j0 = 0x7fffffff, j1 = 0x7fffffff, j2 = 0x7fffffff,
            j3 = 0x7fffffff, j4 = 0x7fffffff, j5 = 0x7fffffff;
#pragma unroll
        for (int s = 0; s < 4; ++s) {
#pragma unroll
            for (int k = 0; k < 6; ++k) {
                const float d = md[t][s][k];
                const int q = mi[t][s][k];
                if (d < e5 || (d == e5 && q < j5)) {
                    if (d < e4 || (d == e4 && q < j4)) {
                        e5 = e4; j5 = j4;
                        if (d < e3 || (d == e3 && q < j3)) {
                            e4 = e3; j4 = j3;
                            if (d < e2 || (d == e2 && q < j2)) {
                                e3 = e2; j3 = j2;
                                if (d < e1 || (d == e1 && q < j1)) {
                                    e2 = e1; j2 = j1;
                                    if (d < e0 || (d == e0 && q < j0)) {
                                        e1 = e0; j1 = j0; e0 = d; j0 = q;
                                    } else { e1 = d; j1 = q; }
                                } else { e2 = d; j2 = q; }
                            } else { e3 = d; j3 = q; }
                        } else { e4 = d; j4 = q; }
                    } else { e5 = d; j5 = q; }
                }
            }
        }
        const int gb = b * NP;
        int* op = idx + (size_t)(gb + chunk * 64 + t) * 6;
        op[0] = gb + j0; op[1] = gb + j1; op[2] = gb + j2;
        op[3] = gb + j3; op[4] = gb + j4; op[5] = gb + j5;
    }
}

// ---------------------------------------------------------------------------
// Kernel 2: layer-1 U precompute: bigU[i][c] = b1[c] + pos_i @ (W1a - W1c).
// W1 is 9x64: rows 0-2 = h_i part, 3-5 = h_j part, 6-8 = rel part.
// ---------------------------------------------------------------------------
__global__ __launch_bounds__(256) void prep1_kernel(
    const float* __restrict__ pos, const float* __restrict__ W1,
    const float* __restrict__ b1, float* __restrict__ Uout)
{
    const int gid = blockIdx.x * 256 + threadIdx.x;
    const int i = gid >> 6;
    const int c = gid & 63;
    const float px = pos[i * 3 + 0], py = pos[i * 3 + 1], pz = pos[i * 3 + 2];
    float u = b1[c];
    u = fmaf(px, W1[0 * 64 + c] - W1[6 * 64 + c], u);
    u = fmaf(py, W1[1 * 64 + c] - W1[7 * 64 + c], u);
    u = fmaf(pz, W1[2 * 64 + c] - W1[8 * 64 + c], u);
    Uout[(size_t)i * 64 + c] = u;
}

// ---------------------------------------------------------------------------
// Kernel 3: U/V precompute for Cin=64 layers with rel folded in:
//   U[i][c] = b1[c] + H_i@W1a - pos_i@W1c      (in place over H)
//   V[j][c] =         H_j@W1b + pos_j@W1c
// Wave-per-point, lane = channel, readlane broadcasts.
// ---------------------------------------------------------------------------
__global__ __launch_bounds__(256) void uv_kernel(
    float* __restrict__ h, float* __restrict__ Vout,
    const float* __restrict__ pos,
    const float* __restrict__ W1, const float* __restrict__ b1)
{
    const int t = threadIdx.x;
    const int lane = t & 63;
    const int wv = __builtin_amdgcn_readfirstlane(t >> 6);

    float w1a[64], w1b[64];
#pragma unroll
    for (int k = 0; k < 64; ++k) w1a[k] = W1[k * 64 + lane];
#pragma unroll
    for (int k = 0; k < 64; ++k) w1b[k] = W1[(64 + k) * 64 + lane];
    const float wc0 = W1[128 * 64 + lane];
    const float wc1 = W1[129 * 64 + lane];
    const float wc2 = W1[130 * 64 + lane];
    const float b1r = b1[lane];

    const int base = blockIdx.x * 64 + wv * 16;
    for (int n = 0; n < 16; ++n) {
        const int i = base + n;
        const float px = pos[i * 3 + 0], py = pos[i * 3 + 1], pz = pos[i * 3 + 2];
        const float tv = h[(size_t)i * 64 + lane];
        float zu0 = b1r, zu1 = 0.f, zv0 = 0.f, zv1 = 0.f;
#pragma unroll
        for (int k = 0; k < 64; k += 2) {
            const float s0 = bcastf(tv, k + 0);
            const float s1 = bcastf(tv, k + 1);
            zu0 = fmaf(s0, w1a[k + 0], zu0);
            zv0 = fmaf(s0, w1b[k + 0], zv0);
            zu1 = fmaf(s1, w1a[k + 1], zu1);
            zv1 = fmaf(s1, w1b[k + 1], zv1);
        }
        float zu = zu0 + zu1, zv = zv0 + zv1;
        zu = fmaf(-px, wc0, zu); zu = fmaf(-py, wc1, zu); zu = fmaf(-pz, wc2, zu);
        zv = fmaf( px, wc0, zv); zv = fmaf( py, wc1, zv); zv = fmaf( pz, wc2, zv);
        h[(size_t)i * 64 + lane] = zu;
        Vout[(size_t)i * 64 + lane] = zv;
    }
}

// ---------------------------------------------------------------------------
// Kernel 4: MFMA edge kernel. Per 16-edge tile (PT points x KP padded nbrs):
//   t_e = relu(U[i] + V[j])   (layer1: relu(U[i] + pos_j@(W1b+W1c)))
//   z   = T(16x64) @ W2(64x64) via split-bf16 MFMA (hi*hi + hi*lo + lo*hi)
//   h_out[point][c] = relu(max_k z + b2)
// T round-trips through wave-private LDS: row = [hi 128B | lo 128B | pad 16B].
// A-frag: A[m=lane&15][k=quad*8+j]; B-frag: B[k=quad*8+j][n=lane&15];
// C/D: row=quad*4+reg, col=lane&15  (rows = edges; point grouping by quad).
// Dummy edges (k >= KREAL) duplicate neighbor 0 -> max unchanged.
// ---------------------------------------------------------------------------
template <int PT, int KP, int KREAL, bool L1>
__global__ __launch_bounds__(256) void edge_mfma_kernel(
    const float* __restrict__ U, const float* __restrict__ V,
    const float* __restrict__ pos, const int* __restrict__ idx,
    const float* __restrict__ W1, const float* __restrict__ W2,
    const float* __restrict__ b2, float* __restrict__ hout, int TPW)
{
    __shared__ char ldsbuf[4 * 16 * 272];
    const int t = threadIdx.x;
    const int lane = t & 63;
    const int wv = __builtin_amdgcn_readfirstlane(t >> 6);
    char* base = &ldsbuf[wv * 16 * 272];
    const int col = lane & 15;
    const int quad = lane >> 4;
    constexpr int KSH = (KP == 8) ? 3 : 2;

    // ---- B-frags: W2 as split-bf16, held in VGPRs -------------------------
    v8s bh[4][2], bl[4][2];
#pragma unroll
    for (int nt = 0; nt < 4; ++nt) {
#pragma unroll
        for (int ks = 0; ks < 2; ++ks) {
            float w[8];
#pragma unroll
            for (int j = 0; j < 8; ++j)
                w[j] = W2[(size_t)(ks * 32 + quad * 8 + j) * 64 + nt * 16 + col];
            union { v8s v; unsigned int u[4]; } H, L;
#pragma unroll
            for (int p = 0; p < 4; ++p) {
                unsigned int a = __float_as_uint(w[2 * p]);
                unsigned int b = __float_as_uint(w[2 * p + 1]);
                unsigned int ha = a & 0xffff0000u, hb = b & 0xffff0000u;
                H.u[p] = (ha >> 16) | hb;
                float la = w[2 * p] - __uint_as_float(ha);
                float lb = w[2 * p + 1] - __uint_as_float(hb);
                L.u[p] = (__float_as_uint(la) >> 16) | (__float_as_uint(lb) & 0xffff0000u);
            }
            bh[nt][ks] = H.v;
            bl[nt][ks] = L.v;
        }
    }
    float b2v[4];
#pragma unroll
    for (int nt = 0; nt < 4; ++nt) b2v[nt] = b2[nt * 16 + col];

    float wb0 = 0.f, wb1 = 0.f, wb2 = 0.f;
    if (L1) {
        wb0 = W1[3 * 64 + lane] + W1[6 * 64 + lane];
        wb1 = W1[4 * 64 + lane] + W1[7 * 64 + lane];
        wb2 = W1[5 * 64 + lane] + W1[8 * 64 + lane];
    }

    for (int tt = 0; tt < TPW; ++tt) {
        const int tile = (blockIdx.x * 4 + wv) * TPW + tt;
        const int pb = tile * PT;

        float u[PT];
#pragma unroll
        for (int p = 0; p < PT; ++p) u[p] = U[(size_t)(pb + p) * 64 + lane];

        // ---- build T (split-bf16) in wave-private LDS ---------------------
#pragma unroll
        for (int e = 0; e < 16; ++e) {
            const int p = e >> KSH;
            int k = e & (KP - 1);
            if (k >= KREAL) k = 0;
            const int j = __builtin_amdgcn_readfirstlane(idx[(size_t)(pb + p) * 6 + k]);
            float tv;
            if (L1) {
                const float pjx = pos[j * 3 + 0], pjy = pos[j * 3 + 1], pjz = pos[j * 3 + 2];
                tv = u[p];
                tv = fmaf(pjx, wb0, tv);
                tv = fmaf(pjy, wb1, tv);
                tv = fmaf(pjz, wb2, tv);
            } else {
                tv = u[p] + V[(size_t)j * 64 + lane];
            }
            tv = fmaxf(tv, 0.0f);
            const unsigned int tu = __float_as_uint(tv);
            const unsigned int hi = tu & 0xffff0000u;
            const float lo = tv - __uint_as_float(hi);
            *((short*)(base + e * 272) + lane)       = (short)(hi >> 16);
            *((short*)(base + e * 272 + 128) + lane) = (short)(__float_as_uint(lo) >> 16);
        }
        __builtin_amdgcn_wave_barrier();
        __builtin_amdgcn_s_waitcnt(0xc07f);   // lgkmcnt(0): LDS writes drained

        // ---- A-frags ------------------------------------------------------
        v8s ah[2], al[2];
#pragma unroll
        for (int ks = 0; ks < 2; ++ks) {
            ah[ks] = *(const v8s*)(base + (lane & 15) * 272 + ks * 64 + quad * 16);
            al[ks] = *(const v8s*)(base + (lane & 15) * 272 + 128 + ks * 64 + quad * 16);
        }

        // ---- MFMA: T @ W2 (3-product split) -------------------------------
        f32x4 acc[4];
#pragma unroll
        for (int nt = 0; nt < 4; ++nt) acc[nt] = (f32x4){0.f, 0.f, 0.f, 0.f};
#pragma unroll
        for (int nt = 0; nt < 4; ++nt) {
#pragma unroll
            for (int ks = 0; ks < 2; ++ks) {
                acc[nt] = __builtin_amdgcn_mfma_f32_16x16x32_bf16(ah[ks], bh[nt][ks], acc[nt], 0, 0, 0);
                acc[nt] = __builtin_amdgcn_mfma_f32_16x16x32_bf16(ah[ks], bl[nt][ks], acc[nt], 0, 0, 0);
                acc[nt] = __builtin_amdgcn_mfma_f32_16x16x32_bf16(al[ks], bh[nt][ks], acc[nt], 0, 0, 0);
            }
        }

        // ---- epilogue: neighbor-max + b2 + relu + store -------------------
#pragma unroll
        for (int nt = 0; nt < 4; ++nt) {
            float m = fmaxf(fmaxf(acc[nt].x, acc[nt].y), fmaxf(acc[nt].z, acc[nt].w));
            if (KP == 4) {
                const float z = fmaxf(m + b2v[nt], 0.0f);
                hout[(size_t)(pb + quad) * 64 + nt * 16 + col] = z;
            } else {
                m = fmaxf(m, __shfl_xor(m, 16));
                const float z = fmaxf(m + b2v[nt], 0.0f);
                if ((lane & 16) == 0)
                    hout[(size_t)(pb + (lane >> 5)) * 64 + nt * 16 + col] = z;
            }
        }
    }
}

// ---------------------------------------------------------------------------
// Kernel 5: global max pool over points + 64->6 regression. One block/graph.
// ---------------------------------------------------------------------------
__global__ __launch_bounds__(256) void pool_reg_kernel(
    const float* __restrict__ h3, const float* __restrict__ regW,
    const float* __restrict__ regb, float* __restrict__ out)
{
    __shared__ float red[4][64];
    __shared__ float pooled[64];
    const int b = blockIdx.x;
    const int t = threadIdx.x;
    const int c = t & 63;
    const int seg = t >> 6;
    const float* hb = h3 + (size_t)b * NP * 64;
    float m = -1e30f;
    for (int p = seg; p < NP; p += 4) m = fmaxf(m, hb[(size_t)p * 64 + c]);
    red[seg][c] = m;
    __syncthreads();
    if (t < 64) {
        pooled[t] = fmaxf(fmaxf(red[0][t], red[1][t]), fmaxf(red[2][t], red[3][t]));
    }
    __syncthreads();
    if (t < 6) {
        float z = regb[t];
        for (int cc = 0; cc < 64; ++cc) z += pooled[cc] * regW[cc * 6 + t];
        out[b * 6 + t] = z;
    }
}

// ---------------------------------------------------------------------------
extern "C" void kernel_launch(void* const* d_in, const int* in_sizes, int n_in,
                              void* d_out, int out_size, void* d_ws, size_t ws_size,
                              hipStream_t stream)
{
    (void)in_sizes; (void)n_in; (void)out_size; (void)ws_size;
    const float* pos   = (const float*)d_in[1];
    const float* c1W1  = (const float*)d_in[3];
    const float* c1b1  = (const float*)d_in[4];
    const float* c1W2  = (const float*)d_in[5];
    const float* c1b2  = (const float*)d_in[6];
    const float* c2W1  = (const float*)d_in[7];
    const float* c2b1  = (const float*)d_in[8];
    const float* c2W2  = (const float*)d_in[9];
    const float* c2b2  = (const float*)d_in[10];
    const float* c3W1  = (const float*)d_in[11];
    const float* c3b1  = (const float*)d_in[12];
    const float* c3W2  = (const float*)d_in[13];
    const float* c3b2  = (const float*)d_in[14];
    const float* regW  = (const float*)d_in[15];
    const float* regb  = (const float*)d_in[16];
    float* out = (float*)d_out;

    // workspace: idx | A | C | D  (A,C,D are 65536x64 fp32)
    char* ws = (char*)d_ws;
    int*   idx = (int*)ws;                                    // 1572864 B
    float* A = (float*)(ws + 1572864);
    float* C = (float*)(ws + 1572864 + 16777216);
    float* D = (float*)(ws + 1572864 + 2 * 16777216);

    knn6_kernel<<<NB * 16, 256, 0, stream>>>(pos, idx);

    // layer 1: bigU1 -> D; edges (PT=2, KP=8, K=6) -> A
    prep1_kernel<<<NPTS * 64 / 256, 256, 0, stream>>>(pos, c1W1, c1b1, D);
    edge_mfma_kernel<2, 8, 6, true><<<1024, 256, 0, stream>>>(
        D, nullptr, pos, idx, c1W1, c1W2, c1b2, A, 8);

    // layer 2: U2 in-place over A, V2 -> C; edges (PT=4, KP=4, K=4) -> D
    uv_kernel<<<NPTS / 64, 256, 0, stream>>>(A, C, pos, c2W1, c2b1);
    edge_mfma_kernel<4, 4, 4, false><<<1024, 256, 0, stream>>>(
        A, C, pos, idx, nullptr, c2W2, c2b2, D, 4);

    // layer 3: U3 in-place over D, V3 -> C; edges (PT=4, KP=4, K=3) -> A
    uv_kernel<<<NPTS / 64, 256, 0, stream>>>(D, C, pos, c3W1, c3b1);
    edge_mfma_kernel<4, 4, 3, false><<<1024, 256, 0, stream>>>(
        D, C, pos, idx, nullptr, c3W2, c3b2, A, 4);

    pool_reg_kernel<<<NB, 256, 0, stream>>>(A, regW, regb, out);
}

// Round 5
// 308.862 us; speedup vs baseline: 5.3908x; 1.0671x over previous
//
#include <hip/hip_runtime.h>
#include <cstddef>

#define NB 64
#define NP 1024
#define NPTS (NB * NP)

typedef __attribute__((ext_vector_type(8))) short v8s;
typedef __attribute__((ext_vector_type(4))) float f32x4;

__device__ __forceinline__ float bcastf(float v, int l) {
    return __int_as_float(__builtin_amdgcn_readlane(__float_as_int(v), l));
}

// ---------------------------------------------------------------------------
// Kernel 1: top-6 kNN per point (self included, top_k-stable tie order).
// One block = 64 points of one graph, 4 scanner threads per point.
// BRANCHLESS insert: sorted d0<=..<=d5 updated with v_med3_f32 (1 inst/level),
// indices with predicated selects. Strict < + ascending q preserves the exact
// (d2, index) lexicographic selection of jax.lax.top_k (verified absmax 0 in
// the fp32 rounds). Merge of the 4 scanners is exact lexicographic.
// ---------------------------------------------------------------------------
__global__ __launch_bounds__(256) void knn6_kernel(const float* __restrict__ pos,
                                                   int* __restrict__ idx)
{
    __shared__ float4 pts[NP];
    __shared__ float md[64][4][6];
    __shared__ int   mi[64][4][6];

    const int blk = blockIdx.x;
    const int b = blk >> 4;
    const int chunk = blk & 15;
    const int t = threadIdx.x;
    const float* gp = pos + (size_t)b * NP * 3;
    for (int q = t; q < NP; q += 256) {
        float x = gp[q * 3 + 0], y = gp[q * 3 + 1], z = gp[q * 3 + 2];
        pts[q] = make_float4(x, y, z, x * x + y * y + z * z);
    }
    __syncthreads();

    const int p = t >> 2;
    const int sub = t & 3;
    const int il = chunk * 64 + p;
    const float4 pi = pts[il];
    const float sqi = pi.w;

    float d0 = 1e30f, d1 = 1e30f, d2v = 1e30f, d3 = 1e30f, d4 = 1e30f, d5 = 1e30f;
    int i0 = 0, i1 = 0, i2 = 0, i3 = 0, i4 = 0, i5 = 0;

    for (int it = 0; it < 256; ++it) {
        const int q = (it << 2) | sub;
        float4 pq = pts[q];
        float dot = pi.x * pq.x + pi.y * pq.y + pi.z * pq.z;
        float dq = fmaf(-2.0f, dot, sqi + pq.w);

        const bool b0 = dq < d0, b1 = dq < d1, b2 = dq < d2v,
                   b3 = dq < d3, b4 = dq < d4, b5 = dq < d5;

        d5  = __builtin_amdgcn_fmed3f(dq, d4, d5);
        d4  = __builtin_amdgcn_fmed3f(dq, d3, d4);
        d3  = __builtin_amdgcn_fmed3f(dq, d2v, d3);
        d2v = __builtin_amdgcn_fmed3f(dq, d1, d2v);
        d1  = __builtin_amdgcn_fmed3f(dq, d0, d1);
        d0  = fminf(dq, d0);

        i5 = b4 ? i4 : (b5 ? q : i5);
        i4 = b3 ? i3 : (b4 ? q : i4);
        i3 = b2 ? i2 : (b3 ? q : i3);
        i2 = b1 ? i1 : (b2 ? q : i2);
        i1 = b0 ? i0 : (b1 ? q : i1);
        i0 = b0 ? q : i0;
    }

    md[p][sub][0] = d0; md[p][sub][1] = d1; md[p][sub][2] = d2v;
    md[p][sub][3] = d3; md[p][sub][4] = d4; md[p][sub][5] = d5;
    mi[p][sub][0] = i0; mi[p][sub][1] = i1; mi[p][sub][2] = i2;
    mi[p][sub][3] = i3; mi[p][sub][4] = i4; mi[p][sub][5] = i5;
    __syncthreads();

    if (t < 64) {
        float e0 = 1e30f, e1 = 1e30f, e2 = 1e30f, e3 = 1e30f, e4 = 1e30f, e5 = 1e30f;
        int j0 = 0x7fffffff, j1 = 0x7fffffff, j2 = 0x7fffffff,
            j3 = 0x7fffffff, j4 = 0x7fffffff, j5 = 0x7fffffff;
#pragma unroll
        for (int s = 0; s < 4; ++s) {
#pragma unroll
            for (int k = 0; k < 6; ++k) {
                const float d = md[t][s][k];
                const int q = mi[t][s][k];
                if (d < e5 || (d == e5 && q < j5)) {
                    if (d < e4 || (d == e4 && q < j4)) {
                        e5 = e4; j5 = j4;
                        if (d < e3 || (d == e3 && q < j3)) {
                            e4 = e3; j4 = j3;
                            if (d < e2 || (d == e2 && q < j2)) {
                                e3 = e2; j3 = j2;
                                if (d < e1 || (d == e1 && q < j1)) {
                                    e2 = e1; j2 = j1;
                                    if (d < e0 || (d == e0 && q < j0)) {
                                        e1 = e0; j1 = j0; e0 = d; j0 = q;
                                    } else { e1 = d; j1 = q; }
                                } else { e2 = d; j2 = q; }
                            } else { e3 = d; j3 = q; }
                        } else { e4 = d; j4 = q; }
                    } else { e5 = d; j5 = q; }
                }
            }
        }
        const int gb = b * NP;
        int* op = idx + (size_t)(gb + chunk * 64 + t) * 6;
        op[0] = gb + j0; op[1] = gb + j1; op[2] = gb + j2;
        op[3] = gb + j3; op[4] = gb + j4; op[5] = gb + j5;
    }
}

// ---------------------------------------------------------------------------
// Kernel 2: layer-1 U precompute: bigU[i][c] = b1[c] + pos_i @ (W1a - W1c).
// ---------------------------------------------------------------------------
__global__ __launch_bounds__(256) void prep1_kernel(
    const float* __restrict__ pos, const float* __restrict__ W1,
    const float* __restrict__ b1, float* __restrict__ Uout)
{
    const int gid = blockIdx.x * 256 + threadIdx.x;
    const int i = gid >> 6;
    const int c = gid & 63;
    const float px = pos[i * 3 + 0], py = pos[i * 3 + 1], pz = pos[i * 3 + 2];
    float u = b1[c];
    u = fmaf(px, W1[0 * 64 + c] - W1[6 * 64 + c], u);
    u = fmaf(py, W1[1 * 64 + c] - W1[7 * 64 + c], u);
    u = fmaf(pz, W1[2 * 64 + c] - W1[8 * 64 + c], u);
    Uout[(size_t)i * 64 + c] = u;
}

// ---------------------------------------------------------------------------
// Kernel 3: U/V precompute for Cin=64 layers with rel folded in:
//   U[i][c] = b1[c] + H_i@W1a - pos_i@W1c      (in place over H)
//   V[j][c] =         H_j@W1b + pos_j@W1c
// ---------------------------------------------------------------------------
__global__ __launch_bounds__(256) void uv_kernel(
    float* __restrict__ h, float* __restrict__ Vout,
    const float* __restrict__ pos,
    const float* __restrict__ W1, const float* __restrict__ b1)
{
    const int t = threadIdx.x;
    const int lane = t & 63;
    const int wv = __builtin_amdgcn_readfirstlane(t >> 6);

    float w1a[64], w1b[64];
#pragma unroll
    for (int k = 0; k < 64; ++k) w1a[k] = W1[k * 64 + lane];
#pragma unroll
    for (int k = 0; k < 64; ++k) w1b[k] = W1[(64 + k) * 64 + lane];
    const float wc0 = W1[128 * 64 + lane];
    const float wc1 = W1[129 * 64 + lane];
    const float wc2 = W1[130 * 64 + lane];
    const float b1r = b1[lane];

    const int base = blockIdx.x * 64 + wv * 16;
    for (int n = 0; n < 16; ++n) {
        const int i = base + n;
        const float px = pos[i * 3 + 0], py = pos[i * 3 + 1], pz = pos[i * 3 + 2];
        const float tv = h[(size_t)i * 64 + lane];
        float zu0 = b1r, zu1 = 0.f, zv0 = 0.f, zv1 = 0.f;
#pragma unroll
        for (int k = 0; k < 64; k += 2) {
            const float s0 = bcastf(tv, k + 0);
            const float s1 = bcastf(tv, k + 1);
            zu0 = fmaf(s0, w1a[k + 0], zu0);
            zv0 = fmaf(s0, w1b[k + 0], zv0);
            zu1 = fmaf(s1, w1a[k + 1], zu1);
            zv1 = fmaf(s1, w1b[k + 1], zv1);
        }
        float zu = zu0 + zu1, zv = zv0 + zv1;
        zu = fmaf(-px, wc0, zu); zu = fmaf(-py, wc1, zu); zu = fmaf(-pz, wc2, zu);
        zv = fmaf( px, wc0, zv); zv = fmaf( py, wc1, zv); zv = fmaf( pz, wc2, zv);
        h[(size_t)i * 64 + lane] = zu;
        Vout[(size_t)i * 64 + lane] = zv;
    }
}

// ---------------------------------------------------------------------------
// Kernel 4: MFMA edge kernel (unchanged from R4).
// ---------------------------------------------------------------------------
template <int PT, int KP, int KREAL, bool L1>
__global__ __launch_bounds__(256) void edge_mfma_kernel(
    const float* __restrict__ U, const float* __restrict__ V,
    const float* __restrict__ pos, const int* __restrict__ idx,
    const float* __restrict__ W1, const float* __restrict__ W2,
    const float* __restrict__ b2, float* __restrict__ hout, int TPW)
{
    __shared__ char ldsbuf[4 * 16 * 272];
    const int t = threadIdx.x;
    const int lane = t & 63;
    const int wv = __builtin_amdgcn_readfirstlane(t >> 6);
    char* base = &ldsbuf[wv * 16 * 272];
    const int col = lane & 15;
    const int quad = lane >> 4;
    constexpr int KSH = (KP == 8) ? 3 : 2;

    v8s bh[4][2], bl[4][2];
#pragma unroll
    for (int nt = 0; nt < 4; ++nt) {
#pragma unroll
        for (int ks = 0; ks < 2; ++ks) {
            float w[8];
#pragma unroll
            for (int j = 0; j < 8; ++j)
                w[j] = W2[(size_t)(ks * 32 + quad * 8 + j) * 64 + nt * 16 + col];
            union { v8s v; unsigned int u[4]; } H, L;
#pragma unroll
            for (int p = 0; p < 4; ++p) {
                unsigned int a = __float_as_uint(w[2 * p]);
                unsigned int b = __float_as_uint(w[2 * p + 1]);
                unsigned int ha = a & 0xffff0000u, hb = b & 0xffff0000u;
                H.u[p] = (ha >> 16) | hb;
                float la = w[2 * p] - __uint_as_float(ha);
                float lb = w[2 * p + 1] - __uint_as_float(hb);
                L.u[p] = (__float_as_uint(la) >> 16) | (__float_as_uint(lb) & 0xffff0000u);
            }
            bh[nt][ks] = H.v;
            bl[nt][ks] = L.v;
        }
    }
    float b2v[4];
#pragma unroll
    for (int nt = 0; nt < 4; ++nt) b2v[nt] = b2[nt * 16 + col];

    float wb0 = 0.f, wb1 = 0.f, wb2 = 0.f;
    if (L1) {
        wb0 = W1[3 * 64 + lane] + W1[6 * 64 + lane];
        wb1 = W1[4 * 64 + lane] + W1[7 * 64 + lane];
        wb2 = W1[5 * 64 + lane] + W1[8 * 64 + lane];
    }

    for (int tt = 0; tt < TPW; ++tt) {
        const int tile = (blockIdx.x * 4 + wv) * TPW + tt;
        const int pb = tile * PT;

        float u[PT];
#pragma unroll
        for (int p = 0; p < PT; ++p) u[p] = U[(size_t)(pb + p) * 64 + lane];

#pragma unroll
        for (int e = 0; e < 16; ++e) {
            const int p = e >> KSH;
            int k = e & (KP - 1);
            if (k >= KREAL) k = 0;
            const int j = __builtin_amdgcn_readfirstlane(idx[(size_t)(pb + p) * 6 + k]);
            float tv;
            if (L1) {
                const float pjx = pos[j * 3 + 0], pjy = pos[j * 3 + 1], pjz = pos[j * 3 + 2];
                tv = u[p];
                tv = fmaf(pjx, wb0, tv);
                tv = fmaf(pjy, wb1, tv);
                tv = fmaf(pjz, wb2, tv);
            } else {
                tv = u[p] + V[(size_t)j * 64 + lane];
            }
            tv = fmaxf(tv, 0.0f);
            const unsigned int tu = __float_as_uint(tv);
            const unsigned int hi = tu & 0xffff0000u;
            const float lo = tv - __uint_as_float(hi);
            *((short*)(base + e * 272) + lane)       = (short)(hi >> 16);
            *((short*)(base + e * 272 + 128) + lane) = (short)(__float_as_uint(lo) >> 16);
        }
        __builtin_amdgcn_wave_barrier();
        __builtin_amdgcn_s_waitcnt(0xc07f);

        v8s ah[2], al[2];
#pragma unroll
        for (int ks = 0; ks < 2; ++ks) {
            ah[ks] = *(const v8s*)(base + (lane & 15) * 272 + ks * 64 + quad * 16);
            al[ks] = *(const v8s*)(base + (lane & 15) * 272 + 128 + ks * 64 + quad * 16);
        }

        f32x4 acc[4];
#pragma unroll
        for (int nt = 0; nt < 4; ++nt) acc[nt] = (f32x4){0.f, 0.f, 0.f, 0.f};
#pragma unroll
        for (int nt = 0; nt < 4; ++nt) {
#pragma unroll
            for (int ks = 0; ks < 2; ++ks) {
                acc[nt] = __builtin_amdgcn_mfma_f32_16x16x32_bf16(ah[ks], bh[nt][ks], acc[nt], 0, 0, 0);
                acc[nt] = __builtin_amdgcn_mfma_f32_16x16x32_bf16(ah[ks], bl[nt][ks], acc[nt], 0, 0, 0);
                acc[nt] = __builtin_amdgcn_mfma_f32_16x16x32_bf16(al[ks], bh[nt][ks], acc[nt], 0, 0, 0);
            }
        }

#pragma unroll
        for (int nt = 0; nt < 4; ++nt) {
            float m = fmaxf(fmaxf(acc[nt].x, acc[nt].y), fmaxf(acc[nt].z, acc[nt].w));
            if (KP == 4) {
                const float z = fmaxf(m + b2v[nt], 0.0f);
                hout[(size_t)(pb + quad) * 64 + nt * 16 + col] = z;
            } else {
                m = fmaxf(m, __shfl_xor(m, 16));
                const float z = fmaxf(m + b2v[nt], 0.0f);
                if ((lane & 16) == 0)
                    hout[(size_t)(pb + (lane >> 5)) * 64 + nt * 16 + col] = z;
            }
        }
    }
}

// ---------------------------------------------------------------------------
// Kernel 5: global max pool over points + 64->6 regression. One block/graph.
// ---------------------------------------------------------------------------
__global__ __launch_bounds__(256) void pool_reg_kernel(
    const float* __restrict__ h3, const float* __restrict__ regW,
    const float* __restrict__ regb, float* __restrict__ out)
{
    __shared__ float red[4][64];
    __shared__ float pooled[64];
    const int b = blockIdx.x;
    const int t = threadIdx.x;
    const int c = t & 63;
    const int seg = t >> 6;
    const float* hb = h3 + (size_t)b * NP * 64;
    float m = -1e30f;
    for (int p = seg; p < NP; p += 4) m = fmaxf(m, hb[(size_t)p * 64 + c]);
    red[seg][c] = m;
    __syncthreads();
    if (t < 64) {
        pooled[t] = fmaxf(fmaxf(red[0][t], red[1][t]), fmaxf(red[2][t], red[3][t]));
    }
    __syncthreads();
    if (t < 6) {
        float z = regb[t];
        for (int cc = 0; cc < 64; ++cc) z += pooled[cc] * regW[cc * 6 + t];
        out[b * 6 + t] = z;
    }
}

// ---------------------------------------------------------------------------
extern "C" void kernel_launch(void* const* d_in, const int* in_sizes, int n_in,
                              void* d_out, int out_size, void* d_ws, size_t ws_size,
                              hipStream_t stream)
{
    (void)in_sizes; (void)n_in; (void)out_size; (void)ws_size;
    const float* pos   = (const float*)d_in[1];
    const float* c1W1  = (const float*)d_in[3];
    const float* c1b1  = (const float*)d_in[4];
    const float* c1W2  = (const float*)d_in[5];
    const float* c1b2  = (const float*)d_in[6];
    const float* c2W1  = (const float*)d_in[7];
    const float* c2b1  = (const float*)d_in[8];
    const float* c2W2  = (const float*)d_in[9];
    const float* c2b2  = (const float*)d_in[10];
    const float* c3W1  = (const float*)d_in[11];
    const float* c3b1  = (const float*)d_in[12];
    const float* c3W2  = (const float*)d_in[13];
    const float* c3b2  = (const float*)d_in[14];
    const float* regW  = (const float*)d_in[15];
    const float* regb  = (const float*)d_in[16];
    float* out = (float*)d_out;

    char* ws = (char*)d_ws;
    int*   idx = (int*)ws;
    float* A = (float*)(ws + 1572864);
    float* C = (float*)(ws + 1572864 + 16777216);
    float* D = (float*)(ws + 1572864 + 2 * 16777216);

    knn6_kernel<<<NB * 16, 256, 0, stream>>>(pos, idx);

    prep1_kernel<<<NPTS * 64 / 256, 256, 0, stream>>>(pos, c1W1, c1b1, D);
    edge_mfma_kernel<2, 8, 6, true><<<1024, 256, 0, stream>>>(
        D, nullptr, pos, idx, c1W1, c1W2, c1b2, A, 8);

    uv_kernel<<<NPTS / 64, 256, 0, stream>>>(A, C, pos, c2W1, c2b1);
    edge_mfma_kernel<4, 4, 4, false><<<1024, 256, 0, stream>>>(
        A, C, pos, idx, nullptr, c2W2, c2b2, D, 4);

    uv_kernel<<<NPTS / 64, 256, 0, stream>>>(D, C, pos, c3W1, c3b1);
    edge_mfma_kernel<4, 4, 3, false><<<1024, 256, 0, stream>>>(
        D, C, pos, idx, nullptr, c3W2, c3b2, A, 4);

    pool_reg_kernel<<<NB, 256, 0, stream>>>(A, regW, regb, out);
}

// Round 6
// 295.092 us; speedup vs baseline: 5.6424x; 1.0467x over previous
//
#include <hip/hip_runtime.h>
#include <cstddef>

#define NB 64
#define NP 1024
#define NPTS (NB * NP)

typedef __attribute__((ext_vector_type(8))) short v8s;
typedef __attribute__((ext_vector_type(4))) float f32x4;

__device__ __forceinline__ float bcastf(float v, int l) {
    return __int_as_float(__builtin_amdgcn_readlane(__float_as_int(v), l));
}

__device__ __forceinline__ float dist2(const float4 pi, const float sqi, const float4 pq) {
    // identical expression in every pass -> bit-identical dq for the same (i,q)
    const float dot = fmaf(pi.z, pq.z, fmaf(pi.y, pq.y, pi.x * pq.x));
    return fmaf(-2.0f, dot, sqi + pq.w);
}

// ---------------------------------------------------------------------------
// Kernel 1: top-6 kNN, two-pass.
//  pass 1: 4 scanners/point keep only sorted top-6 DISTANCES (med3 chain,
//          ~11 VALU/candidate, no index tracking).
//  merge:  24 scanner distances -> per-point threshold th = 6th smallest.
//  pass 2: rescan, collect indices with dq <= th (rare -> execz-skipped).
//  final:  exact lexicographic (d, q) merge of survivors == jax.lax.top_k.
// ---------------------------------------------------------------------------
__global__ __launch_bounds__(256) void knn6_kernel(const float* __restrict__ pos,
                                                   int* __restrict__ idx)
{
    __shared__ float4 pts[NP];       // 16 KB
    __shared__ float  sd[256 * 6];   // 6 KB  scanner top-6 distances
    __shared__ float  thr[64];       // per-point threshold
    __shared__ int    ci[256 * 8];   // 8 KB  pass-2 survivor indices
    __shared__ int    cn[256];       // pass-2 counts

    const int blk = blockIdx.x;
    const int b = blk >> 4;
    const int chunk = blk & 15;
    const int t = threadIdx.x;
    const float* gp = pos + (size_t)b * NP * 3;
    for (int q = t; q < NP; q += 256) {
        float x = gp[q * 3 + 0], y = gp[q * 3 + 1], z = gp[q * 3 + 2];
        pts[q] = make_float4(x, y, z, x * x + y * y + z * z);
    }
    __syncthreads();

    const int p = t >> 2;
    const int sub = t & 3;
    const int il = chunk * 64 + p;
    const float4 pi = pts[il];
    const float sqi = pi.w;

    // ---- pass 1: distances only --------------------------------------------
    float d0 = 1e30f, d1 = 1e30f, d2v = 1e30f, d3 = 1e30f, d4 = 1e30f, d5 = 1e30f;
#pragma unroll 4
    for (int it = 0; it < 256; ++it) {
        const int q = (it << 2) | sub;
        const float dq = dist2(pi, sqi, pts[q]);
        d5  = __builtin_amdgcn_fmed3f(dq, d4, d5);
        d4  = __builtin_amdgcn_fmed3f(dq, d3, d4);
        d3  = __builtin_amdgcn_fmed3f(dq, d2v, d3);
        d2v = __builtin_amdgcn_fmed3f(dq, d1, d2v);
        d1  = __builtin_amdgcn_fmed3f(dq, d0, d1);
        d0  = fminf(dq, d0);
    }
    {
        float* sp = &sd[t * 6];
        sp[0] = d0; sp[1] = d1; sp[2] = d2v; sp[3] = d3; sp[4] = d4; sp[5] = d5;
    }
    __syncthreads();

    // ---- threshold: 6th smallest of the 24 merged distances ----------------
    if (t < 64) {
        float e0 = 1e30f, e1 = 1e30f, e2 = 1e30f, e3 = 1e30f, e4 = 1e30f, e5 = 1e30f;
#pragma unroll
        for (int s = 0; s < 4; ++s) {
            const float* q6 = &sd[(t * 4 + s) * 6];
#pragma unroll
            for (int k = 0; k < 6; ++k) {
                const float d = q6[k];
                e5 = __builtin_amdgcn_fmed3f(d, e4, e5);
                e4 = __builtin_amdgcn_fmed3f(d, e3, e4);
                e3 = __builtin_amdgcn_fmed3f(d, e2, e3);
                e2 = __builtin_amdgcn_fmed3f(d, e1, e2);
                e1 = __builtin_amdgcn_fmed3f(d, e0, e1);
                e0 = fminf(d, e0);
            }
        }
        thr[t] = e5;
    }
    __syncthreads();

    // ---- pass 2: collect survivor indices ----------------------------------
    const float th = thr[p];
    int cnt = 0;
#pragma unroll 4
    for (int it = 0; it < 256; ++it) {
        const int q = (it << 2) | sub;
        const float dq = dist2(pi, sqi, pts[q]);
        if (dq <= th) {
            ci[t * 8 + (cnt & 7)] = q;
            ++cnt;
        }
    }
    cn[t] = (cnt > 8) ? 8 : cnt;
    __syncthreads();

    // ---- final exact lexicographic merge -----------------------------------
    if (t < 64) {
        const float4 pit = pts[chunk * 64 + t];
        const float sqit = pit.w;
        float e0 = 1e30f, e1 = 1e30f, e2 = 1e30f, e3 = 1e30f, e4 = 1e30f, e5 = 1e30f;
        int j0 = 0x7fffffff, j1 = 0x7fffffff, j2 = 0x7fffffff,
            j3 = 0x7fffffff, j4 = 0x7fffffff, j5 = 0x7fffffff;
#pragma unroll
        for (int s = 0; s < 4; ++s) {
            const int tid = t * 4 + s;
            const int n = cn[tid];
            for (int e = 0; e < n; ++e) {
                const int q = ci[tid * 8 + e];
                const float d = dist2(pit, sqit, pts[q]);
                if (d < e5 || (d == e5 && q < j5)) {
                    if (d < e4 || (d == e4 && q < j4)) {
                        e5 = e4; j5 = j4;
                        if (d < e3 || (d == e3 && q < j3)) {
                            e4 = e3; j4 = j3;
                            if (d < e2 || (d == e2 && q < j2)) {
                                e3 = e2; j3 = j2;
                                if (d < e1 || (d == e1 && q < j1)) {
                                    e2 = e1; j2 = j1;
                                    if (d < e0 || (d == e0 && q < j0)) {
                                        e1 = e0; j1 = j0; e0 = d; j0 = q;
                                    } else { e1 = d; j1 = q; }
                                } else { e2 = d; j2 = q; }
                            } else { e3 = d; j3 = q; }
                        } else { e4 = d; j4 = q; }
                    } else { e5 = d; j5 = q; }
                }
            }
        }
        const int gb = b * NP;
        int* op = idx + (size_t)(gb + chunk * 64 + t) * 6;
        op[0] = gb + j0; op[1] = gb + j1; op[2] = gb + j2;
        op[3] = gb + j3; op[4] = gb + j4; op[5] = gb + j5;
    }
}

// ---------------------------------------------------------------------------
// Kernel 2: layer-1 U precompute: bigU[i][c] = b1[c] + pos_i @ (W1a - W1c).
// ---------------------------------------------------------------------------
__global__ __launch_bounds__(256) void prep1_kernel(
    const float* __restrict__ pos, const float* __restrict__ W1,
    const float* __restrict__ b1, float* __restrict__ Uout)
{
    const int gid = blockIdx.x * 256 + threadIdx.x;
    const int i = gid >> 6;
    const int c = gid & 63;
    const float px = pos[i * 3 + 0], py = pos[i * 3 + 1], pz = pos[i * 3 + 2];
    float u = b1[c];
    u = fmaf(px, W1[0 * 64 + c] - W1[6 * 64 + c], u);
    u = fmaf(py, W1[1 * 64 + c] - W1[7 * 64 + c], u);
    u = fmaf(pz, W1[2 * 64 + c] - W1[8 * 64 + c], u);
    Uout[(size_t)i * 64 + c] = u;
}

// ---------------------------------------------------------------------------
// Kernel 3: U/V precompute for Cin=64 layers with rel folded in:
//   U[i][c] = b1[c] + H_i@W1a - pos_i@W1c      (in place over H)
//   V[j][c] =         H_j@W1b + pos_j@W1c
// ---------------------------------------------------------------------------
__global__ __launch_bounds__(256) void uv_kernel(
    float* __restrict__ h, float* __restrict__ Vout,
    const float* __restrict__ pos,
    const float* __restrict__ W1, const float* __restrict__ b1)
{
    const int t = threadIdx.x;
    const int lane = t & 63;
    const int wv = __builtin_amdgcn_readfirstlane(t >> 6);

    float w1a[64], w1b[64];
#pragma unroll
    for (int k = 0; k < 64; ++k) w1a[k] = W1[k * 64 + lane];
#pragma unroll
    for (int k = 0; k < 64; ++k) w1b[k] = W1[(64 + k) * 64 + lane];
    const float wc0 = W1[128 * 64 + lane];
    const float wc1 = W1[129 * 64 + lane];
    const float wc2 = W1[130 * 64 + lane];
    const float b1r = b1[lane];

    const int base = blockIdx.x * 64 + wv * 16;
    for (int n = 0; n < 16; ++n) {
        const int i = base + n;
        const float px = pos[i * 3 + 0], py = pos[i * 3 + 1], pz = pos[i * 3 + 2];
        const float tv = h[(size_t)i * 64 + lane];
        float zu0 = b1r, zu1 = 0.f, zv0 = 0.f, zv1 = 0.f;
#pragma unroll
        for (int k = 0; k < 64; k += 2) {
            const float s0 = bcastf(tv, k + 0);
            const float s1 = bcastf(tv, k + 1);
            zu0 = fmaf(s0, w1a[k + 0], zu0);
            zv0 = fmaf(s0, w1b[k + 0], zv0);
            zu1 = fmaf(s1, w1a[k + 1], zu1);
            zv1 = fmaf(s1, w1b[k + 1], zv1);
        }
        float zu = zu0 + zu1, zv = zv0 + zv1;
        zu = fmaf(-px, wc0, zu); zu = fmaf(-py, wc1, zu); zu = fmaf(-pz, wc2, zu);
        zv = fmaf( px, wc0, zv); zv = fmaf( py, wc1, zv); zv = fmaf( pz, wc2, zv);
        h[(size_t)i * 64 + lane] = zu;
        Vout[(size_t)i * 64 + lane] = zv;
    }
}

// ---------------------------------------------------------------------------
// Kernel 4: MFMA edge kernel (unchanged).
// ---------------------------------------------------------------------------
template <int PT, int KP, int KREAL, bool L1>
__global__ __launch_bounds__(256) void edge_mfma_kernel(
    const float* __restrict__ U, const float* __restrict__ V,
    const float* __restrict__ pos, const int* __restrict__ idx,
    const float* __restrict__ W1, const float* __restrict__ W2,
    const float* __restrict__ b2, float* __restrict__ hout, int TPW)
{
    __shared__ char ldsbuf[4 * 16 * 272];
    const int t = threadIdx.x;
    const int lane = t & 63;
    const int wv = __builtin_amdgcn_readfirstlane(t >> 6);
    char* base = &ldsbuf[wv * 16 * 272];
    const int col = lane & 15;
    const int quad = lane >> 4;
    constexpr int KSH = (KP == 8) ? 3 : 2;

    v8s bh[4][2], bl[4][2];
#pragma unroll
    for (int nt = 0; nt < 4; ++nt) {
#pragma unroll
        for (int ks = 0; ks < 2; ++ks) {
            float w[8];
#pragma unroll
            for (int j = 0; j < 8; ++j)
                w[j] = W2[(size_t)(ks * 32 + quad * 8 + j) * 64 + nt * 16 + col];
            union { v8s v; unsigned int u[4]; } H, L;
#pragma unroll
            for (int p = 0; p < 4; ++p) {
                unsigned int a = __float_as_uint(w[2 * p]);
                unsigned int b = __float_as_uint(w[2 * p + 1]);
                unsigned int ha = a & 0xffff0000u, hb = b & 0xffff0000u;
                H.u[p] = (ha >> 16) | hb;
                float la = w[2 * p] - __uint_as_float(ha);
                float lb = w[2 * p + 1] - __uint_as_float(hb);
                L.u[p] = (__float_as_uint(la) >> 16) | (__float_as_uint(lb) & 0xffff0000u);
            }
            bh[nt][ks] = H.v;
            bl[nt][ks] = L.v;
        }
    }
    float b2v[4];
#pragma unroll
    for (int nt = 0; nt < 4; ++nt) b2v[nt] = b2[nt * 16 + col];

    float wb0 = 0.f, wb1 = 0.f, wb2 = 0.f;
    if (L1) {
        wb0 = W1[3 * 64 + lane] + W1[6 * 64 + lane];
        wb1 = W1[4 * 64 + lane] + W1[7 * 64 + lane];
        wb2 = W1[5 * 64 + lane] + W1[8 * 64 + lane];
    }

    for (int tt = 0; tt < TPW; ++tt) {
        const int tile = (blockIdx.x * 4 + wv) * TPW + tt;
        const int pb = tile * PT;

        float u[PT];
#pragma unroll
        for (int p = 0; p < PT; ++p) u[p] = U[(size_t)(pb + p) * 64 + lane];

#pragma unroll
        for (int e = 0; e < 16; ++e) {
            const int p = e >> KSH;
            int k = e & (KP - 1);
            if (k >= KREAL) k = 0;
            const int j = __builtin_amdgcn_readfirstlane(idx[(size_t)(pb + p) * 6 + k]);
            float tv;
            if (L1) {
                const float pjx = pos[j * 3 + 0], pjy = pos[j * 3 + 1], pjz = pos[j * 3 + 2];
                tv = u[p];
                tv = fmaf(pjx, wb0, tv);
                tv = fmaf(pjy, wb1, tv);
                tv = fmaf(pjz, wb2, tv);
            } else {
                tv = u[p] + V[(size_t)j * 64 + lane];
            }
            tv = fmaxf(tv, 0.0f);
            const unsigned int tu = __float_as_uint(tv);
            const unsigned int hi = tu & 0xffff0000u;
            const float lo = tv - __uint_as_float(hi);
            *((short*)(base + e * 272) + lane)       = (short)(hi >> 16);
            *((short*)(base + e * 272 + 128) + lane) = (short)(__float_as_uint(lo) >> 16);
        }
        __builtin_amdgcn_wave_barrier();
        __builtin_amdgcn_s_waitcnt(0xc07f);

        v8s ah[2], al[2];
#pragma unroll
        for (int ks = 0; ks < 2; ++ks) {
            ah[ks] = *(const v8s*)(base + (lane & 15) * 272 + ks * 64 + quad * 16);
            al[ks] = *(const v8s*)(base + (lane & 15) * 272 + 128 + ks * 64 + quad * 16);
        }

        f32x4 acc[4];
#pragma unroll
        for (int nt = 0; nt < 4; ++nt) acc[nt] = (f32x4){0.f, 0.f, 0.f, 0.f};
#pragma unroll
        for (int nt = 0; nt < 4; ++nt) {
#pragma unroll
            for (int ks = 0; ks < 2; ++ks) {
                acc[nt] = __builtin_amdgcn_mfma_f32_16x16x32_bf16(ah[ks], bh[nt][ks], acc[nt], 0, 0, 0);
                acc[nt] = __builtin_amdgcn_mfma_f32_16x16x32_bf16(ah[ks], bl[nt][ks], acc[nt], 0, 0, 0);
                acc[nt] = __builtin_amdgcn_mfma_f32_16x16x32_bf16(al[ks], bh[nt][ks], acc[nt], 0, 0, 0);
            }
        }

#pragma unroll
        for (int nt = 0; nt < 4; ++nt) {
            float m = fmaxf(fmaxf(acc[nt].x, acc[nt].y), fmaxf(acc[nt].z, acc[nt].w));
            if (KP == 4) {
                const float z = fmaxf(m + b2v[nt], 0.0f);
                hout[(size_t)(pb + quad) * 64 + nt * 16 + col] = z;
            } else {
                m = fmaxf(m, __shfl_xor(m, 16));
                const float z = fmaxf(m + b2v[nt], 0.0f);
                if ((lane & 16) == 0)
                    hout[(size_t)(pb + (lane >> 5)) * 64 + nt * 16 + col] = z;
            }
        }
    }
}

// ---------------------------------------------------------------------------
// Kernel 5: global max pool over points + 64->6 regression. One block/graph.
// ---------------------------------------------------------------------------
__global__ __launch_bounds__(256) void pool_reg_kernel(
    const float* __restrict__ h3, const float* __restrict__ regW,
    const float* __restrict__ regb, float* __restrict__ out)
{
    __shared__ float red[4][64];
    __shared__ float pooled[64];
    const int b = blockIdx.x;
    const int t = threadIdx.x;
    const int c = t & 63;
    const int seg = t >> 6;
    const float* hb = h3 + (size_t)b * NP * 64;
    float m = -1e30f;
    for (int p = seg; p < NP; p += 4) m = fmaxf(m, hb[(size_t)p * 64 + c]);
    red[seg][c] = m;
    __syncthreads();
    if (t < 64) {
        pooled[t] = fmaxf(fmaxf(red[0][t], red[1][t]), fmaxf(red[2][t], red[3][t]));
    }
    __syncthreads();
    if (t < 6) {
        float z = regb[t];
        for (int cc = 0; cc < 64; ++cc) z += pooled[cc] * regW[cc * 6 + t];
        out[b * 6 + t] = z;
    }
}

// ---------------------------------------------------------------------------
extern "C" void kernel_launch(void* const* d_in, const int* in_sizes, int n_in,
                              void* d_out, int out_size, void* d_ws, size_t ws_size,
                              hipStream_t stream)
{
    (void)in_sizes; (void)n_in; (void)out_size; (void)ws_size;
    const float* pos   = (const float*)d_in[1];
    const float* c1W1  = (const float*)d_in[3];
    const float* c1b1  = (const float*)d_in[4];
    const float* c1W2  = (const float*)d_in[5];
    const float* c1b2  = (const float*)d_in[6];
    const float* c2W1  = (const float*)d_in[7];
    const float* c2b1  = (const float*)d_in[8];
    const float* c2W2  = (const float*)d_in[9];
    const float* c2b2  = (const float*)d_in[10];
    const float* c3W1  = (const float*)d_in[11];
    const float* c3b1  = (const float*)d_in[12];
    const float* c3W2  = (const float*)d_in[13];
    const float* c3b2  = (const float*)d_in[14];
    const float* regW  = (const float*)d_in[15];
    const float* regb  = (const float*)d_in[16];
    float* out = (float*)d_out;

    char* ws = (char*)d_ws;
    int*   idx = (int*)ws;
    float* A = (float*)(ws + 1572864);
    float* C = (float*)(ws + 1572864 + 16777216);
    float* D = (float*)(ws + 1572864 + 2 * 16777216);

    knn6_kernel<<<NB * 16, 256, 0, stream>>>(pos, idx);

    prep1_kernel<<<NPTS * 64 / 256, 256, 0, stream>>>(pos, c1W1, c1b1, D);
    edge_mfma_kernel<2, 8, 6, true><<<1024, 256, 0, stream>>>(
        D, nullptr, pos, idx, c1W1, c1W2, c1b2, A, 8);

    uv_kernel<<<NPTS / 64, 256, 0, stream>>>(A, C, pos, c2W1, c2b1);
    edge_mfma_kernel<4, 4, 4, false><<<1024, 256, 0, stream>>>(
        A, C, pos, idx, nullptr, c2W2, c2b2, D, 4);

    uv_kernel<<<NPTS / 64, 256, 0, stream>>>(D, C, pos, c3W1, c3b1);
    edge_mfma_kernel<4, 4, 3, false><<<1024, 256, 0, stream>>>(
        D, C, pos, idx, nullptr, c3W2, c3b2, A, 4);

    pool_reg_kernel<<<NB, 256, 0, stream>>>(A, regW, regb, out);
}